// Round 1
// baseline (155.238 us; speedup 1.0000x reference)
//
#include <hip/hip_runtime.h>
#include <hip/hip_bf16.h>

#define N_PITCH 576
#define D_MODEL 128

// Prep: WT2[p*128 + d] = W[d*577 + p] + b[d]   for p in [0,576)
//       WT2[576*128 + d] = W[d*577 + 576]      (gain weight, no bias)
__global__ void prep_kernel(const float* __restrict__ W,
                            const float* __restrict__ b,
                            float* __restrict__ WT) {
    int i = blockIdx.x * blockDim.x + threadIdx.x;
    const int total = (N_PITCH + 1) * D_MODEL;
    if (i < total) {
        int p = i >> 7;        // / 128
        int d = i & 127;       // % 128
        float v = W[d * (N_PITCH + 1) + p];
        if (p < N_PITCH) v += b[d];
        WT[i] = v;
    }
}

// Hot kernel: one 32-lane group per token; lane handles one float4 (4 of 128 dims).
__global__ void __launch_bounds__(256)
encode_kernel(const int* __restrict__ pitch,
              const float* __restrict__ gain,
              const float* __restrict__ WT,
              float* __restrict__ out,
              int ntok) {
    const float4* __restrict__ WT4 = (const float4*)WT;           // [577][32]
    const float4* __restrict__ WG4 = WT4 + N_PITCH * (D_MODEL / 4); // gain row
    float4* __restrict__ out4 = (float4*)out;

    int lane = threadIdx.x & 31;
    int grp  = (blockIdx.x * blockDim.x + threadIdx.x) >> 5;
    int ngrp = (gridDim.x * blockDim.x) >> 5;

    float4 wg = WG4[lane];  // invariant across tokens

    for (int j = grp; j < ntok; j += ngrp) {
        int   p = pitch[j];   // broadcast within group
        float g = gain[j];
        float4 w = WT4[p * (D_MODEL / 4) + lane];
        float4 r;
        r.x = fmaf(g, wg.x, w.x);
        r.y = fmaf(g, wg.y, w.y);
        r.z = fmaf(g, wg.z, w.z);
        r.w = fmaf(g, wg.w, w.w);
        out4[j * (D_MODEL / 4) + lane] = r;
    }
}

extern "C" void kernel_launch(void* const* d_in, const int* in_sizes, int n_in,
                              void* d_out, int out_size, void* d_ws, size_t ws_size,
                              hipStream_t stream) {
    const int*   pitch = (const int*)d_in[0];
    const float* gain  = (const float*)d_in[1];
    const float* W     = (const float*)d_in[2];
    const float* b     = (const float*)d_in[3];
    float* out = (float*)d_out;
    float* WT  = (float*)d_ws;   // (577)*128 floats = 295,424 B

    int ntok = in_sizes[0];      // B*S = 262144

    const int prep_total = (N_PITCH + 1) * D_MODEL;
    prep_kernel<<<(prep_total + 255) / 256, 256, 0, stream>>>(W, b, WT);

    int blocks = 2048;           // persistent, grid-stride (8 tokens per 256-thr block/iter)
    encode_kernel<<<blocks, 256, 0, stream>>>(pitch, gain, WT, out, ntok);
}